// Round 9
// baseline (286.394 us; speedup 1.0000x reference)
//
#include <hip/hip_runtime.h>

#define N_NODES 50000
#define N_EDGES 800000
#define FEA 128
#define NL 3
#define AH 512
#define NG 64
#define NBLK 196   // ceil(50000/256)

typedef short bf16x8 __attribute__((ext_vector_type(8)));
typedef float f32x4 __attribute__((ext_vector_type(4)));
typedef uint  u32x4 __attribute__((ext_vector_type(4)));

__device__ __forceinline__ ushort f2bf(float f) {   // RTN-even
    uint u = __float_as_uint(f);
    uint r = u + 0x7FFFu + ((u >> 16) & 1u);
    return (ushort)(r >> 16);
}
__device__ __forceinline__ float bf2f(ushort u) {
    return __uint_as_float((uint)u << 16);
}

// ---------------- degree histogram + per-edge rank ----------------
__global__ void k_deg(const int* __restrict__ dst, int* __restrict__ deg,
                      int* __restrict__ rank) {
    int i = blockIdx.x * blockDim.x + threadIdx.x;
    if (i < N_EDGES) rank[i] = atomicAdd(&deg[dst[i]], 1);
}

// ---------------- 3-kernel exclusive scan over PADDED degrees ----------------
__device__ __forceinline__ int block_scan_incl(int v, int* wsum) {
    int lane = threadIdx.x & 63, w = threadIdx.x >> 6;
    int s = v;
#pragma unroll
    for (int off = 1; off < 64; off <<= 1) {
        int t = __shfl_up(s, off);
        if (lane >= off) s += t;
    }
    if (lane == 63) wsum[w] = s;
    __syncthreads();
    int woff = 0;
    for (int k = 0; k < w; ++k) woff += wsum[k];
    return woff + s;  // block-wide inclusive
}

__global__ __launch_bounds__(256) void k_scan1(const int* __restrict__ deg,
                                               int* __restrict__ rowptr,
                                               int* __restrict__ bsum,
                                               float* __restrict__ dinv) {
    __shared__ int wsum[4];
    int i = blockIdx.x * 256 + threadIdx.x;
    int v = (i < N_NODES) ? deg[i] : 0;
    int pv = (v + 7) & ~7;                       // pad to multiple of 8
    int incl = block_scan_incl(pv, wsum);
    if (i < N_NODES) {
        rowptr[i] = incl - pv;                   // local exclusive
        dinv[i] = rsqrtf((float)v + 1.0f);
    }
    if (threadIdx.x == 255) bsum[blockIdx.x] = incl;
}

__global__ __launch_bounds__(256) void k_scan2(int* __restrict__ bsum,
                                               int* __restrict__ boff,
                                               int* __restrict__ rowptr) {
    __shared__ int wsum[4];
    int v = (threadIdx.x < NBLK) ? bsum[threadIdx.x] : 0;
    int incl = block_scan_incl(v, wsum);
    if (threadIdx.x < NBLK) boff[threadIdx.x] = incl - v;
    if (threadIdx.x == NBLK - 1) rowptr[N_NODES] = incl;  // total padded edges
}

__global__ __launch_bounds__(256) void k_scan3(int* __restrict__ rowptr,
                                               const int* __restrict__ boff) {
    int i = blockIdx.x * 256 + threadIdx.x;
    if (i < N_NODES) rowptr[i] += boff[blockIdx.x];
}

// ---------------- CSR fill (no atomics) ----------------
__global__ void k_fill(const int* __restrict__ src, const int* __restrict__ dst,
                       const int* __restrict__ rowptr, const int* __restrict__ rank,
                       ushort* __restrict__ eidx) {
    int e = blockIdx.x * blockDim.x + threadIdx.x;
    if (e < N_EDGES) eidx[rowptr[dst[e]] + rank[e]] = (ushort)src[e];
}

// ---------------- fused prep: x->hi/lo planes, padfill, bounds, w1T/w2T,
//                  W split-transpose, H pad-row zero ----------------
#define PA 6250            // x conversion: 6250 blocks * 1024 elems
#define PB (PA + NBLK)     // padfill
#define PC (PB + NBLK)     // bounds
#define PD (PC + 512)      // w1T/w2T
#define PE (PD + 192)      // conv W split-transpose (3*16384 elems)
#define PF (PE + 1)        // pad row zero
__global__ __launch_bounds__(256) void k_prep(const float* __restrict__ x,
                                              const int* __restrict__ batch,
                                              const int* __restrict__ deg,
                                              const int* __restrict__ rowptr,
                                              const float* __restrict__ convW,
                                              const float* __restrict__ w1,
                                              const float* __restrict__ w2,
                                              ushort* __restrict__ eidx,
                                              int* __restrict__ gstart,
                                              ushort* __restrict__ Xhi,
                                              ushort* __restrict__ Xlo,
                                              ushort* __restrict__ WhiT,
                                              ushort* __restrict__ WloT,
                                              float* __restrict__ w1T,
                                              float* __restrict__ w2T,
                                              ushort* __restrict__ H) {
    int blk = blockIdx.x;
    if (blk < PA) {                        // x -> Xhi/Xlo (4 elems/thread)
        int i4 = blk * 1024 + threadIdx.x * 4;
        float4 v = *(const float4*)(x + i4);
        ushort h0 = f2bf(v.x), h1 = f2bf(v.y), h2 = f2bf(v.z), h3 = f2bf(v.w);
        uint2 hv, lv;
        hv.x = (uint)h0 | ((uint)h1 << 16);
        hv.y = (uint)h2 | ((uint)h3 << 16);
        lv.x = (uint)f2bf(v.x - bf2f(h0)) | ((uint)f2bf(v.y - bf2f(h1)) << 16);
        lv.y = (uint)f2bf(v.z - bf2f(h2)) | ((uint)f2bf(v.w - bf2f(h3)) << 16);
        *(uint2*)(Xhi + i4) = hv;
        *(uint2*)(Xlo + i4) = lv;
    } else if (blk < PB) {                 // padfill
        int i = (blk - PA) * 256 + threadIdx.x;
        if (i < N_NODES) {
            int d = deg[i], r = rowptr[i];
            int pd = (d + 7) & ~7;
            for (int k = d; k < pd; ++k) eidx[r + k] = (ushort)N_NODES;
        }
    } else if (blk < PC) {                 // bounds
        int i = (blk - PB) * 256 + threadIdx.x;
        if (i < N_NODES) {
            int b = batch[i];
            int bp = (i == 0) ? -1 : batch[i - 1];
            for (int g = bp + 1; g <= b; ++g) gstart[g] = i;
            if (i == N_NODES - 1)
                for (int g = b + 1; g <= NG; ++g) gstart[g] = N_NODES;
        }
    } else if (blk < PD) {                 // w1T / w2T transpose
        int idx = (blk - PC) * 256 + threadIdx.x;   // 0..131071
        if (idx < FEA * AH) {
            int k = idx >> 9, j = idx & 511;
            w1T[(size_t)j * FEA + k] = w1[idx];
        } else {
            int t = idx - FEA * AH;
            int k = t >> 7, f = t & 127;
            w2T[(size_t)f * AH + k] = w2[t];
        }
    } else if (blk < PE) {                 // conv W split-transpose
        int t = (blk - PD) * 256 + threadIdx.x;     // 0..49151
        int l = t >> 14, r = t & 16383;
        int k = r >> 7, c = r & 127;
        float w = convW[t];
        ushort h = f2bf(w);
        WhiT[(size_t)l * 16384 + c * FEA + k] = h;
        WloT[(size_t)l * 16384 + c * FEA + k] = f2bf(w - bf2f(h));
    } else {                               // zero H pad row (128 bf16)
        if (threadIdx.x < 64) ((uint*)(H + (size_t)N_NODES * FEA))[threadIdx.x] = 0;
    }
}

// ---------------- MFMA GEMM: H'(bf16) = dinv * (X @ W) ----------------
// A and B pre-split to bf16 hi/lo planes; inner loop = pure loads + MFMA.
__global__ __launch_bounds__(256) void k_gemm(const ushort* __restrict__ Xhi,
                                              const ushort* __restrict__ Xlo,
                                              const ushort* __restrict__ WhiT,
                                              const ushort* __restrict__ WloT,
                                              const float* __restrict__ dinv,
                                              ushort* __restrict__ H) {
    const int wv = threadIdx.x >> 6;
    const int lane = threadIdx.x & 63;
    const int lr = lane & 15;
    const int lk = lane >> 4;

    bf16x8 bhi[2][4], blo[2][4];
#pragma unroll
    for (int ct = 0; ct < 2; ++ct) {
        int col = wv * 32 + ct * 16 + lr;
#pragma unroll
        for (int kf = 0; kf < 4; ++kf) {
            bhi[ct][kf] = *(const bf16x8*)(WhiT + (size_t)col * FEA + kf * 32 + lk * 8);
            blo[ct][kf] = *(const bf16x8*)(WloT + (size_t)col * FEA + kf * 32 + lk * 8);
        }
    }

    for (int rt = blockIdx.x; rt < N_NODES / 16; rt += gridDim.x) {
        int r0 = rt * 16;
        const ushort* xh = Xhi + (size_t)(r0 + lr) * FEA;
        const ushort* xl = Xlo + (size_t)(r0 + lr) * FEA;
        bf16x8 ahi[4], alo[4];
#pragma unroll
        for (int kf = 0; kf < 4; ++kf) {
            ahi[kf] = *(const bf16x8*)(xh + kf * 32 + lk * 8);
            alo[kf] = *(const bf16x8*)(xl + kf * 32 + lk * 8);
        }
        f32x4 acc0 = {0.f, 0.f, 0.f, 0.f};
        f32x4 acc1 = {0.f, 0.f, 0.f, 0.f};
#pragma unroll
        for (int kf = 0; kf < 4; ++kf) {
            acc0 = __builtin_amdgcn_mfma_f32_16x16x32_bf16(ahi[kf], bhi[0][kf], acc0, 0, 0, 0);
            acc0 = __builtin_amdgcn_mfma_f32_16x16x32_bf16(ahi[kf], blo[0][kf], acc0, 0, 0, 0);
            acc0 = __builtin_amdgcn_mfma_f32_16x16x32_bf16(alo[kf], bhi[0][kf], acc0, 0, 0, 0);
            acc1 = __builtin_amdgcn_mfma_f32_16x16x32_bf16(ahi[kf], bhi[1][kf], acc1, 0, 0, 0);
            acc1 = __builtin_amdgcn_mfma_f32_16x16x32_bf16(ahi[kf], blo[1][kf], acc1, 0, 0, 0);
            acc1 = __builtin_amdgcn_mfma_f32_16x16x32_bf16(alo[kf], bhi[1][kf], acc1, 0, 0, 0);
        }
#pragma unroll
        for (int reg = 0; reg < 4; ++reg) {
            int orow = r0 + lk * 4 + reg;
            float s = dinv[orow];
            H[(size_t)orow * FEA + wv * 32 + lr]      = f2bf(acc0[reg] * s);
            H[(size_t)orow * FEA + wv * 32 + 16 + lr] = f2bf(acc1[reg] * s);
        }
    }
}

// ---------------- gather: X = relu(dinv*(sum H'[s] + H'[d]) + b), hi/lo planes out ----------------
__global__ __launch_bounds__(256) void k_gather(const int* __restrict__ rowptr,
                                                const ushort* __restrict__ eidx,
                                                const float* __restrict__ dinv,
                                                const ushort* __restrict__ H,
                                                const float* __restrict__ b,
                                                ushort* __restrict__ Xhi,
                                                ushort* __restrict__ Xlo) {
    int t = blockIdx.x * 256 + threadIdx.x;
    int node = t >> 4;
    int c8 = t & 15;
    if (node >= N_NODES) return;
    const uint4* H4 = (const uint4*)H;  // 16 x uint4 per row
    int r0 = rowptr[node], r1 = rowptr[node + 1];

    float a[8] = {0.f, 0.f, 0.f, 0.f, 0.f, 0.f, 0.f, 0.f};
#define ACC8(u)                                                              \
    do {                                                                     \
        a[0] += __uint_as_float((u).x << 16);                                \
        a[1] += __uint_as_float((u).x & 0xffff0000u);                        \
        a[2] += __uint_as_float((u).y << 16);                                \
        a[3] += __uint_as_float((u).y & 0xffff0000u);                        \
        a[4] += __uint_as_float((u).z << 16);                                \
        a[5] += __uint_as_float((u).z & 0xffff0000u);                        \
        a[6] += __uint_as_float((u).w << 16);                                \
        a[7] += __uint_as_float((u).w & 0xffff0000u);                        \
    } while (0)

    uint4 sv = H4[(size_t)node * 16 + c8];  // self term
    ACC8(sv);

    for (int j = r0; j < r1; j += 8) {
        int s0 = eidx[j + 0], s1 = eidx[j + 1];
        int s2 = eidx[j + 2], s3 = eidx[j + 3];
        int s4 = eidx[j + 4], s5 = eidx[j + 5];
        int s6 = eidx[j + 6], s7 = eidx[j + 7];
        uint4 h0 = H4[(size_t)s0 * 16 + c8];
        uint4 h1 = H4[(size_t)s1 * 16 + c8];
        uint4 h2 = H4[(size_t)s2 * 16 + c8];
        uint4 h3 = H4[(size_t)s3 * 16 + c8];
        uint4 h4 = H4[(size_t)s4 * 16 + c8];
        uint4 h5 = H4[(size_t)s5 * 16 + c8];
        uint4 h6 = H4[(size_t)s6 * 16 + c8];
        uint4 h7 = H4[(size_t)s7 * 16 + c8];
        ACC8(h0); ACC8(h1); ACC8(h2); ACC8(h3);
        ACC8(h4); ACC8(h5); ACC8(h6); ACC8(h7);
    }
#undef ACC8

    float di = dinv[node];
    const float4* b4 = (const float4*)b;
    float4 bb0 = b4[c8 * 2], bb1 = b4[c8 * 2 + 1];
    float o[8];
    o[0] = fmaxf(a[0] * di + bb0.x, 0.f);
    o[1] = fmaxf(a[1] * di + bb0.y, 0.f);
    o[2] = fmaxf(a[2] * di + bb0.z, 0.f);
    o[3] = fmaxf(a[3] * di + bb0.w, 0.f);
    o[4] = fmaxf(a[4] * di + bb1.x, 0.f);
    o[5] = fmaxf(a[5] * di + bb1.y, 0.f);
    o[6] = fmaxf(a[6] * di + bb1.z, 0.f);
    o[7] = fmaxf(a[7] * di + bb1.w, 0.f);
    ushort hs[8];
    uint ls[8];
#pragma unroll
    for (int i = 0; i < 8; ++i) {
        hs[i] = f2bf(o[i]);
        ls[i] = f2bf(o[i] - bf2f(hs[i]));
    }
    u32x4 hv, lv;
    hv.x = (uint)hs[0] | ((uint)hs[1] << 16);
    hv.y = (uint)hs[2] | ((uint)hs[3] << 16);
    hv.z = (uint)hs[4] | ((uint)hs[5] << 16);
    hv.w = (uint)hs[6] | ((uint)hs[7] << 16);
    lv.x = ls[0] | (ls[1] << 16);
    lv.y = ls[2] | (ls[3] << 16);
    lv.z = ls[4] | (ls[5] << 16);
    lv.w = ls[6] | (ls[7] << 16);
    __builtin_nontemporal_store(hv, (u32x4*)(Xhi + (size_t)node * FEA + c8 * 8));
    __builtin_nontemporal_store(lv, (u32x4*)(Xlo + (size_t)node * FEA + c8 * 8));
}

// ---------------- per-graph pooled sums + node head (no atomics) ----------------
__global__ __launch_bounds__(256) void k_graph(const ushort* __restrict__ Xhi,
                                               const ushort* __restrict__ Xlo,
                                               const int* __restrict__ gstart,
                                               const float* __restrict__ nw,
                                               const float* __restrict__ nb,
                                               float* __restrict__ out_node,
                                               float* __restrict__ psum_part) {
    int g = blockIdx.x >> 2, p = blockIdx.x & 3;
    int s = gstart[g], e = gstart[g + 1];
    int len = e - s;
    int l4 = (len + 3) >> 2;
    int ps = s + p * l4, pe = min(ps + l4, e);
    int wave = threadIdx.x >> 6, lane = threadIdx.x & 63;
    float2 w = ((const float2*)nw)[lane];
    float nbv = nb[0];
    float2 acc = {0.f, 0.f};
    for (int node = ps + wave; node < pe; node += 4) {
        uint hv = *(const uint*)(Xhi + (size_t)node * FEA + lane * 2);
        uint lv = *(const uint*)(Xlo + (size_t)node * FEA + lane * 2);
        float2 v;
        v.x = bf2f((ushort)hv) + bf2f((ushort)lv);
        v.y = bf2f((ushort)(hv >> 16)) + bf2f((ushort)(lv >> 16));
        acc.x += v.x; acc.y += v.y;
        float dot = v.x * w.x + v.y * w.y;
#pragma unroll
        for (int off = 32; off; off >>= 1) dot += __shfl_down(dot, off);
        if (lane == 0) out_node[node] = dot + nbv;
    }
    __shared__ float lds[4 * FEA];
    lds[wave * FEA + lane * 2 + 0] = acc.x;
    lds[wave * FEA + lane * 2 + 1] = acc.y;
    __syncthreads();
    if (threadIdx.x < FEA) {
        float sum = lds[threadIdx.x] + lds[FEA + threadIdx.x] +
                    lds[2 * FEA + threadIdx.x] + lds[3 * FEA + threadIdx.x];
        psum_part[(size_t)blockIdx.x * FEA + threadIdx.x] = sum;
    }
}

// ---------------- MLP layer 1 ----------------
__global__ __launch_bounds__(256) void k_mlp1(const float* __restrict__ psum_part,
                                              const int* __restrict__ gstart,
                                              const float* __restrict__ w1T,
                                              const float* __restrict__ b1,
                                              float* __restrict__ h1ws) {
    __shared__ float feas[NG * 132];   // pad 132 to spread banks
    for (int idx = threadIdx.x; idx < NG * FEA; idx += 256) {
        int g = idx >> 7, f = idx & 127;
        const float* pp = psum_part + (size_t)g * 4 * FEA + f;
        float cnt = fmaxf((float)(gstart[g + 1] - gstart[g]), 1.0f);
        feas[g * 132 + f] = (pp[0] + pp[FEA] + pp[2 * FEA] + pp[3 * FEA]) / cnt;
    }
    __syncthreads();
    int g = threadIdx.x >> 2, jj = threadIdx.x & 3;
    int j = blockIdx.x * 4 + jj;
    const float4* fr = (const float4*)(feas + g * 132);
    const float4* wr = (const float4*)(w1T + (size_t)j * FEA);
    float4 a0 = {0.f, 0.f, 0.f, 0.f}, a1 = {0.f, 0.f, 0.f, 0.f};
#pragma unroll
    for (int i = 0; i < 16; ++i) {
        float4 f0 = fr[2 * i], w0 = wr[2 * i];
        float4 f1 = fr[2 * i + 1], w1v = wr[2 * i + 1];
        a0.x += f0.x * w0.x; a0.y += f0.y * w0.y;
        a0.z += f0.z * w0.z; a0.w += f0.w * w0.w;
        a1.x += f1.x * w1v.x; a1.y += f1.y * w1v.y;
        a1.z += f1.z * w1v.z; a1.w += f1.w * w1v.w;
    }
    float s = (a0.x + a0.y) + (a0.z + a0.w) + (a1.x + a1.y) + (a1.z + a1.w);
    h1ws[(size_t)g * AH + j] = fmaxf(s + b1[j], 0.f);
}

// ---------------- MLP layer 2 ----------------
__global__ __launch_bounds__(256) void k_mlp2(const float* __restrict__ h1ws,
                                              const float* __restrict__ w2T,
                                              const float* __restrict__ b2,
                                              float* __restrict__ out_fea) {
    int f = blockIdx.x;
    int g = threadIdx.x >> 2, q = threadIdx.x & 3;
    const float4* hr = (const float4*)(h1ws + (size_t)g * AH + q * 128);
    const float4* wr = (const float4*)(w2T + (size_t)f * AH + q * 128);
    float4 a0 = {0.f, 0.f, 0.f, 0.f}, a1 = {0.f, 0.f, 0.f, 0.f};
#pragma unroll
    for (int i = 0; i < 16; ++i) {
        float4 h0 = hr[2 * i], w0 = wr[2 * i];
        float4 h1 = hr[2 * i + 1], w1v = wr[2 * i + 1];
        a0.x += h0.x * w0.x; a0.y += h0.y * w0.y;
        a0.z += h0.z * w0.z; a0.w += h0.w * w0.w;
        a1.x += h1.x * w1v.x; a1.y += h1.y * w1v.y;
        a1.z += h1.z * w1v.z; a1.w += h1.w * w1v.w;
    }
    float p = (a0.x + a0.y) + (a0.z + a0.w) + (a1.x + a1.y) + (a1.z + a1.w);
    p += __shfl_xor(p, 1);
    p += __shfl_xor(p, 2);
    if (q == 0) out_fea[(size_t)g * FEA + f] = p + b2[f];
}

extern "C" void kernel_launch(void* const* d_in, const int* in_sizes, int n_in,
                              void* d_out, int out_size, void* d_ws, size_t ws_size,
                              hipStream_t stream) {
    const float* x     = (const float*)d_in[0];
    const int*   ei    = (const int*)d_in[1];
    const int*   batch = (const int*)d_in[2];
    const float* convW = (const float*)d_in[3];
    const float* convb = (const float*)d_in[4];
    const float* w1    = (const float*)d_in[5];
    const float* b1    = (const float*)d_in[6];
    const float* w2    = (const float*)d_in[7];
    const float* b2    = (const float*)d_in[8];
    const float* nw    = (const float*)d_in[9];
    const float* nb    = (const float*)d_in[10];
    float* out = (float*)d_out;

    // workspace layout (4-byte word offsets)
    char* wsb = (char*)d_ws;
    int*    deg    = (int*)wsb;                        // 50000
    float*  dinv   = (float*)(wsb + 50048ll * 4);      // 50000
    int*    rowptr = (int*)(wsb + 100096ll * 4);       // 50001
    int*    bsum   = (int*)(wsb + 150144ll * 4);       // 196
    int*    boff   = (int*)(wsb + 150344ll * 4);       // 196
    int*    gstart = (int*)(wsb + 150544ll * 4);       // 65
    int*    rank   = (int*)(wsb + 150656ll * 4);       // 800000 words (reused)
    // rank area reuse after k_fill:
    float*  w1T    = (float*)rank;                     // 65536 w
    float*  w2T    = (float*)(rank + 65536);           // 65536 w
    float*  h1ws   = (float*)(rank + 131072);          // 32768 w
    ushort* WhiT   = (ushort*)(rank + 163840);         // 49152 shorts = 24576 w
    ushort* WloT   = (ushort*)(rank + 188416);         // 24576 w
    ushort* eidx   = (ushort*)(wsb + 950656ll * 4);    // <=1.3M ushort
    ushort* H      = (ushort*)(wsb + 1600672ll * 4);   // (50001)*128 bf16
    ushort* Xhi    = (ushort*)(wsb + 4800736ll * 4);   // 6.4M bf16
    ushort* Xlo    = (ushort*)(wsb + 8000736ll * 4);   // 6.4M bf16
    float*  psum_part = (float*)(wsb + 11200736ll * 4);// 256*128

    const int* srcp = ei;
    const int* dstp = ei + N_EDGES;

    // ---- CSR build + prep (once per call) ----
    hipMemsetAsync(deg, 0, N_NODES * sizeof(int), stream);
    k_deg<<<(N_EDGES + 255) / 256, 256, 0, stream>>>(dstp, deg, rank);
    k_scan1<<<NBLK, 256, 0, stream>>>(deg, rowptr, bsum, dinv);
    k_scan2<<<1, 256, 0, stream>>>(bsum, boff, rowptr);
    k_scan3<<<NBLK, 256, 0, stream>>>(rowptr, boff);
    k_fill<<<(N_EDGES + 255) / 256, 256, 0, stream>>>(srcp, dstp, rowptr, rank, eidx);
    k_prep<<<PF, 256, 0, stream>>>(x, batch, deg, rowptr, convW, w1, w2,
                                   eidx, gstart, Xhi, Xlo, WhiT, WloT, w1T, w2T, H);

    // ---- GCN layers ----
    for (int l = 0; l < NL; ++l) {
        k_gemm<<<1024, 256, 0, stream>>>(Xhi, Xlo, WhiT + (size_t)l * 16384,
                                         WloT + (size_t)l * 16384, dinv, H);
        k_gather<<<(N_NODES * 16 + 255) / 256, 256, 0, stream>>>(
            rowptr, eidx, dinv, H, convb + (size_t)l * FEA, Xhi, Xlo);
    }

    // ---- heads ----
    k_graph<<<NG * 4, 256, 0, stream>>>(Xhi, Xlo, gstart, nw, nb, out, psum_part);
    k_mlp1<<<128, 256, 0, stream>>>(psum_part, gstart, w1T, b1, h1ws);
    k_mlp2<<<128, 256, 0, stream>>>(h1ws, w2T, b2, out + N_NODES);
}

// Round 10
// 262.431 us; speedup vs baseline: 1.0913x; 1.0913x over previous
//
#include <hip/hip_runtime.h>

#define N_NODES 50000
#define N_EDGES 800000
#define FEA 128
#define NL 3
#define AH 512
#define NG 64
#define NBLK 196   // ceil(50000/256)

typedef short bf16x8 __attribute__((ext_vector_type(8)));
typedef float f32x4 __attribute__((ext_vector_type(4)));
typedef uint  u32x4 __attribute__((ext_vector_type(4)));

__device__ __forceinline__ ushort f2bf(float f) {   // RTN-even
    uint u = __float_as_uint(f);
    uint r = u + 0x7FFFu + ((u >> 16) & 1u);
    return (ushort)(r >> 16);
}
__device__ __forceinline__ float bf2f(ushort u) {
    return __uint_as_float((uint)u << 16);
}

// ---------------- degree histogram + per-edge rank ----------------
__global__ void k_deg(const int* __restrict__ dst, int* __restrict__ deg,
                      ushort* __restrict__ rank) {
    int i = blockIdx.x * blockDim.x + threadIdx.x;
    if (i < N_EDGES) rank[i] = (ushort)atomicAdd(&deg[dst[i]], 1);
}

// ---------------- 3-kernel exclusive scan over PADDED degrees ----------------
__device__ __forceinline__ int block_scan_incl(int v, int* wsum) {
    int lane = threadIdx.x & 63, w = threadIdx.x >> 6;
    int s = v;
#pragma unroll
    for (int off = 1; off < 64; off <<= 1) {
        int t = __shfl_up(s, off);
        if (lane >= off) s += t;
    }
    if (lane == 63) wsum[w] = s;
    __syncthreads();
    int woff = 0;
    for (int k = 0; k < w; ++k) woff += wsum[k];
    return woff + s;  // block-wide inclusive
}

__global__ __launch_bounds__(256) void k_scan1(const int* __restrict__ deg,
                                               int* __restrict__ rowptr,
                                               int* __restrict__ bsum,
                                               float* __restrict__ dinv) {
    __shared__ int wsum[4];
    int i = blockIdx.x * 256 + threadIdx.x;
    int v = (i < N_NODES) ? deg[i] : 0;
    int pv = (v + 7) & ~7;                       // pad to multiple of 8
    int incl = block_scan_incl(pv, wsum);
    if (i < N_NODES) {
        rowptr[i] = incl - pv;                   // local exclusive
        dinv[i] = rsqrtf((float)v + 1.0f);
    }
    if (threadIdx.x == 255) bsum[blockIdx.x] = incl;
}

__global__ __launch_bounds__(256) void k_scan2(int* __restrict__ bsum,
                                               int* __restrict__ boff,
                                               int* __restrict__ rowptr) {
    __shared__ int wsum[4];
    int v = (threadIdx.x < NBLK) ? bsum[threadIdx.x] : 0;
    int incl = block_scan_incl(v, wsum);
    if (threadIdx.x < NBLK) boff[threadIdx.x] = incl - v;
    if (threadIdx.x == NBLK - 1) rowptr[N_NODES] = incl;  // total padded edges
}

__global__ __launch_bounds__(256) void k_scan3(int* __restrict__ rowptr,
                                               const int* __restrict__ boff) {
    int i = blockIdx.x * 256 + threadIdx.x;
    if (i < N_NODES) rowptr[i] += boff[blockIdx.x];
}

// ---------------- CSR fill (no atomics) ----------------
__global__ void k_fill(const int* __restrict__ src, const int* __restrict__ dst,
                       const int* __restrict__ rowptr, const ushort* __restrict__ rank,
                       ushort* __restrict__ eidx) {
    int e = blockIdx.x * blockDim.x + threadIdx.x;
    if (e < N_EDGES) eidx[rowptr[dst[e]] + (int)rank[e]] = (ushort)src[e];
}

// ---------------- fused prep: x->hi/lo planes, padfill, bounds, w1T/w2T,
//                  W split-transpose, H pad-row zero ----------------
#define PA 6250            // x conversion: 6250 blocks * 1024 elems
#define PB (PA + NBLK)     // padfill
#define PC (PB + NBLK)     // bounds
#define PD (PC + 512)      // w1T/w2T
#define PE (PD + 192)      // conv W split-transpose (3*16384 elems)
#define PF (PE + 1)        // pad row zero
__global__ __launch_bounds__(256) void k_prep(const float* __restrict__ x,
                                              const int* __restrict__ batch,
                                              const int* __restrict__ deg,
                                              const int* __restrict__ rowptr,
                                              const float* __restrict__ convW,
                                              const float* __restrict__ w1,
                                              const float* __restrict__ w2,
                                              ushort* __restrict__ eidx,
                                              int* __restrict__ gstart,
                                              ushort* __restrict__ Xhi,
                                              ushort* __restrict__ Xlo,
                                              ushort* __restrict__ WhiT,
                                              ushort* __restrict__ WloT,
                                              float* __restrict__ w1T,
                                              float* __restrict__ w2T,
                                              ushort* __restrict__ H) {
    int blk = blockIdx.x;
    if (blk < PA) {                        // x -> Xhi/Xlo (4 elems/thread)
        int i4 = blk * 1024 + threadIdx.x * 4;
        float4 v = *(const float4*)(x + i4);
        ushort h0 = f2bf(v.x), h1 = f2bf(v.y), h2 = f2bf(v.z), h3 = f2bf(v.w);
        uint2 hv, lv;
        hv.x = (uint)h0 | ((uint)h1 << 16);
        hv.y = (uint)h2 | ((uint)h3 << 16);
        lv.x = (uint)f2bf(v.x - bf2f(h0)) | ((uint)f2bf(v.y - bf2f(h1)) << 16);
        lv.y = (uint)f2bf(v.z - bf2f(h2)) | ((uint)f2bf(v.w - bf2f(h3)) << 16);
        *(uint2*)(Xhi + i4) = hv;
        *(uint2*)(Xlo + i4) = lv;
    } else if (blk < PB) {                 // padfill
        int i = (blk - PA) * 256 + threadIdx.x;
        if (i < N_NODES) {
            int d = deg[i], r = rowptr[i];
            int pd = (d + 7) & ~7;
            for (int k = d; k < pd; ++k) eidx[r + k] = (ushort)N_NODES;
        }
    } else if (blk < PC) {                 // bounds
        int i = (blk - PB) * 256 + threadIdx.x;
        if (i < N_NODES) {
            int b = batch[i];
            int bp = (i == 0) ? -1 : batch[i - 1];
            for (int g = bp + 1; g <= b; ++g) gstart[g] = i;
            if (i == N_NODES - 1)
                for (int g = b + 1; g <= NG; ++g) gstart[g] = N_NODES;
        }
    } else if (blk < PD) {                 // w1T / w2T transpose
        int idx = (blk - PC) * 256 + threadIdx.x;   // 0..131071
        if (idx < FEA * AH) {
            int k = idx >> 9, j = idx & 511;
            w1T[(size_t)j * FEA + k] = w1[idx];
        } else {
            int t = idx - FEA * AH;
            int k = t >> 7, f = t & 127;
            w2T[(size_t)f * AH + k] = w2[t];
        }
    } else if (blk < PE) {                 // conv W split-transpose
        int t = (blk - PD) * 256 + threadIdx.x;     // 0..49151
        int l = t >> 14, r = t & 16383;
        int k = r >> 7, c = r & 127;
        float w = convW[t];
        ushort h = f2bf(w);
        WhiT[(size_t)l * 16384 + c * FEA + k] = h;
        WloT[(size_t)l * 16384 + c * FEA + k] = f2bf(w - bf2f(h));
    } else {                               // zero H pad row (128 bf16)
        if (threadIdx.x < 64) ((uint*)(H + (size_t)N_NODES * FEA))[threadIdx.x] = 0;
    }
}

// ---------------- MFMA GEMM: H'(bf16) = dinv * (X @ W) ----------------
__global__ __launch_bounds__(256) void k_gemm(const ushort* __restrict__ Xhi,
                                              const ushort* __restrict__ Xlo,
                                              const ushort* __restrict__ WhiT,
                                              const ushort* __restrict__ WloT,
                                              const float* __restrict__ dinv,
                                              ushort* __restrict__ H) {
    const int wv = threadIdx.x >> 6;
    const int lane = threadIdx.x & 63;
    const int lr = lane & 15;
    const int lk = lane >> 4;

    bf16x8 bhi[2][4], blo[2][4];
#pragma unroll
    for (int ct = 0; ct < 2; ++ct) {
        int col = wv * 32 + ct * 16 + lr;
#pragma unroll
        for (int kf = 0; kf < 4; ++kf) {
            bhi[ct][kf] = *(const bf16x8*)(WhiT + (size_t)col * FEA + kf * 32 + lk * 8);
            blo[ct][kf] = *(const bf16x8*)(WloT + (size_t)col * FEA + kf * 32 + lk * 8);
        }
    }

    for (int rt = blockIdx.x; rt < N_NODES / 16; rt += gridDim.x) {
        int r0 = rt * 16;
        const ushort* xh = Xhi + (size_t)(r0 + lr) * FEA;
        const ushort* xl = Xlo + (size_t)(r0 + lr) * FEA;
        bf16x8 ahi[4], alo[4];
#pragma unroll
        for (int kf = 0; kf < 4; ++kf) {
            ahi[kf] = *(const bf16x8*)(xh + kf * 32 + lk * 8);
            alo[kf] = *(const bf16x8*)(xl + kf * 32 + lk * 8);
        }
        f32x4 acc0 = {0.f, 0.f, 0.f, 0.f};
        f32x4 acc1 = {0.f, 0.f, 0.f, 0.f};
#pragma unroll
        for (int kf = 0; kf < 4; ++kf) {
            acc0 = __builtin_amdgcn_mfma_f32_16x16x32_bf16(ahi[kf], bhi[0][kf], acc0, 0, 0, 0);
            acc0 = __builtin_amdgcn_mfma_f32_16x16x32_bf16(ahi[kf], blo[0][kf], acc0, 0, 0, 0);
            acc0 = __builtin_amdgcn_mfma_f32_16x16x32_bf16(alo[kf], bhi[0][kf], acc0, 0, 0, 0);
            acc1 = __builtin_amdgcn_mfma_f32_16x16x32_bf16(ahi[kf], bhi[1][kf], acc1, 0, 0, 0);
            acc1 = __builtin_amdgcn_mfma_f32_16x16x32_bf16(ahi[kf], blo[1][kf], acc1, 0, 0, 0);
            acc1 = __builtin_amdgcn_mfma_f32_16x16x32_bf16(alo[kf], bhi[1][kf], acc1, 0, 0, 0);
        }
#pragma unroll
        for (int reg = 0; reg < 4; ++reg) {
            int orow = r0 + lk * 4 + reg;
            float s = dinv[orow];
            H[(size_t)orow * FEA + wv * 32 + lr]      = f2bf(acc0[reg] * s);
            H[(size_t)orow * FEA + wv * 32 + 16 + lr] = f2bf(acc1[reg] * s);
        }
    }
}

// ---------------- gather (+fused node head on last layer) ----------------
__global__ __launch_bounds__(256) void k_gather(const int* __restrict__ rowptr,
                                                const ushort* __restrict__ eidx,
                                                const float* __restrict__ dinv,
                                                const ushort* __restrict__ H,
                                                const float* __restrict__ b,
                                                ushort* __restrict__ Xhi,
                                                ushort* __restrict__ Xlo,
                                                const float* __restrict__ nw,
                                                const float* __restrict__ nbp,
                                                float* __restrict__ out_node,
                                                int last) {
    int t = blockIdx.x * 256 + threadIdx.x;
    int node = t >> 4;
    int c8 = t & 15;
    if (node >= N_NODES) return;
    const uint4* H4 = (const uint4*)H;  // 16 x uint4 per row
    int r0 = rowptr[node], r1 = rowptr[node + 1];

    float a[8] = {0.f, 0.f, 0.f, 0.f, 0.f, 0.f, 0.f, 0.f};
#define ACC8(u)                                                              \
    do {                                                                     \
        a[0] += __uint_as_float((u).x << 16);                                \
        a[1] += __uint_as_float((u).x & 0xffff0000u);                        \
        a[2] += __uint_as_float((u).y << 16);                                \
        a[3] += __uint_as_float((u).y & 0xffff0000u);                        \
        a[4] += __uint_as_float((u).z << 16);                                \
        a[5] += __uint_as_float((u).z & 0xffff0000u);                        \
        a[6] += __uint_as_float((u).w << 16);                                \
        a[7] += __uint_as_float((u).w & 0xffff0000u);                        \
    } while (0)

    uint4 sv = H4[(size_t)node * 16 + c8];  // self term
    ACC8(sv);

    for (int j = r0; j < r1; j += 8) {
        int s0 = eidx[j + 0], s1 = eidx[j + 1];
        int s2 = eidx[j + 2], s3 = eidx[j + 3];
        int s4 = eidx[j + 4], s5 = eidx[j + 5];
        int s6 = eidx[j + 6], s7 = eidx[j + 7];
        uint4 h0 = H4[(size_t)s0 * 16 + c8];
        uint4 h1 = H4[(size_t)s1 * 16 + c8];
        uint4 h2 = H4[(size_t)s2 * 16 + c8];
        uint4 h3 = H4[(size_t)s3 * 16 + c8];
        uint4 h4 = H4[(size_t)s4 * 16 + c8];
        uint4 h5 = H4[(size_t)s5 * 16 + c8];
        uint4 h6 = H4[(size_t)s6 * 16 + c8];
        uint4 h7 = H4[(size_t)s7 * 16 + c8];
        ACC8(h0); ACC8(h1); ACC8(h2); ACC8(h3);
        ACC8(h4); ACC8(h5); ACC8(h6); ACC8(h7);
    }
#undef ACC8

    float di = dinv[node];
    const float4* b4 = (const float4*)b;
    float4 bb0 = b4[c8 * 2], bb1 = b4[c8 * 2 + 1];
    float o[8];
    o[0] = fmaxf(a[0] * di + bb0.x, 0.f);
    o[1] = fmaxf(a[1] * di + bb0.y, 0.f);
    o[2] = fmaxf(a[2] * di + bb0.z, 0.f);
    o[3] = fmaxf(a[3] * di + bb0.w, 0.f);
    o[4] = fmaxf(a[4] * di + bb1.x, 0.f);
    o[5] = fmaxf(a[5] * di + bb1.y, 0.f);
    o[6] = fmaxf(a[6] * di + bb1.z, 0.f);
    o[7] = fmaxf(a[7] * di + bb1.w, 0.f);

    if (last) {  // fused node head: dot(X[node], nw) via 16-lane group reduce
        const float4* nw4 = (const float4*)nw;
        float4 n0 = nw4[c8 * 2], n1 = nw4[c8 * 2 + 1];
        float dot = o[0] * n0.x + o[1] * n0.y + o[2] * n0.z + o[3] * n0.w
                  + o[4] * n1.x + o[5] * n1.y + o[6] * n1.z + o[7] * n1.w;
        dot += __shfl_xor(dot, 1);
        dot += __shfl_xor(dot, 2);
        dot += __shfl_xor(dot, 4);
        dot += __shfl_xor(dot, 8);
        if (c8 == 0) out_node[node] = dot + nbp[0];
    }

    ushort hs[8];
    uint ls[8];
#pragma unroll
    for (int i = 0; i < 8; ++i) {
        hs[i] = f2bf(o[i]);
        ls[i] = f2bf(o[i] - bf2f(hs[i]));
    }
    u32x4 hv, lv;
    hv.x = (uint)hs[0] | ((uint)hs[1] << 16);
    hv.y = (uint)hs[2] | ((uint)hs[3] << 16);
    hv.z = (uint)hs[4] | ((uint)hs[5] << 16);
    hv.w = (uint)hs[6] | ((uint)hs[7] << 16);
    lv.x = ls[0] | (ls[1] << 16);
    lv.y = ls[2] | (ls[3] << 16);
    lv.z = ls[4] | (ls[5] << 16);
    lv.w = ls[6] | (ls[7] << 16);
    __builtin_nontemporal_store(hv, (u32x4*)(Xhi + (size_t)node * FEA + c8 * 8));
    __builtin_nontemporal_store(lv, (u32x4*)(Xlo + (size_t)node * FEA + c8 * 8));
}

// ---------------- pool-only partial sums: 16 partials per graph ----------------
__global__ __launch_bounds__(256) void k_pool(const ushort* __restrict__ Xhi,
                                              const ushort* __restrict__ Xlo,
                                              const int* __restrict__ gstart,
                                              float* __restrict__ psum_part) {
    int g = blockIdx.x >> 4, p = blockIdx.x & 15;
    int s = gstart[g], e = gstart[g + 1];
    int len = e - s;
    int lp = (len + 15) >> 4;
    int ps = s + p * lp, pe = min(ps + lp, e);
    int q = threadIdx.x >> 6, lane = threadIdx.x & 63;
    float2 acc = {0.f, 0.f};
    for (int node = ps + q; node < pe; node += 4) {
        uint hv = *(const uint*)(Xhi + (size_t)node * FEA + lane * 2);
        uint lv = *(const uint*)(Xlo + (size_t)node * FEA + lane * 2);
        acc.x += bf2f((ushort)hv) + bf2f((ushort)lv);
        acc.y += bf2f((ushort)(hv >> 16)) + bf2f((ushort)(lv >> 16));
    }
    __shared__ float lds[4 * FEA];
    lds[q * FEA + lane * 2 + 0] = acc.x;
    lds[q * FEA + lane * 2 + 1] = acc.y;
    __syncthreads();
    if (threadIdx.x < FEA) {
        psum_part[(size_t)blockIdx.x * FEA + threadIdx.x] =
            lds[threadIdx.x] + lds[FEA + threadIdx.x] +
            lds[2 * FEA + threadIdx.x] + lds[3 * FEA + threadIdx.x];
    }
}

// ---------------- MLP layer 1 ----------------
__global__ __launch_bounds__(256) void k_mlp1(const float* __restrict__ psum_part,
                                              const int* __restrict__ gstart,
                                              const float* __restrict__ w1T,
                                              const float* __restrict__ b1,
                                              float* __restrict__ h1ws) {
    __shared__ float feas[NG * 132];   // pad 132 to spread banks
    for (int idx = threadIdx.x; idx < NG * FEA; idx += 256) {
        int g = idx >> 7, f = idx & 127;
        const float* pp = psum_part + (size_t)g * 16 * FEA + f;
        float sum = 0.f;
#pragma unroll
        for (int p = 0; p < 16; ++p) sum += pp[p * FEA];
        float cnt = fmaxf((float)(gstart[g + 1] - gstart[g]), 1.0f);
        feas[g * 132 + f] = sum / cnt;
    }
    __syncthreads();
    int g = threadIdx.x >> 2, jj = threadIdx.x & 3;
    int j = blockIdx.x * 4 + jj;
    const float4* fr = (const float4*)(feas + g * 132);
    const float4* wr = (const float4*)(w1T + (size_t)j * FEA);
    float4 a0 = {0.f, 0.f, 0.f, 0.f}, a1 = {0.f, 0.f, 0.f, 0.f};
#pragma unroll
    for (int i = 0; i < 16; ++i) {
        float4 f0 = fr[2 * i], w0 = wr[2 * i];
        float4 f1 = fr[2 * i + 1], w1v = wr[2 * i + 1];
        a0.x += f0.x * w0.x; a0.y += f0.y * w0.y;
        a0.z += f0.z * w0.z; a0.w += f0.w * w0.w;
        a1.x += f1.x * w1v.x; a1.y += f1.y * w1v.y;
        a1.z += f1.z * w1v.z; a1.w += f1.w * w1v.w;
    }
    float s = (a0.x + a0.y) + (a0.z + a0.w) + (a1.x + a1.y) + (a1.z + a1.w);
    h1ws[(size_t)g * AH + j] = fmaxf(s + b1[j], 0.f);
}

// ---------------- MLP layer 2 ----------------
__global__ __launch_bounds__(256) void k_mlp2(const float* __restrict__ h1ws,
                                              const float* __restrict__ w2T,
                                              const float* __restrict__ b2,
                                              float* __restrict__ out_fea) {
    int f = blockIdx.x;
    int g = threadIdx.x >> 2, q = threadIdx.x & 3;
    const float4* hr = (const float4*)(h1ws + (size_t)g * AH + q * 128);
    const float4* wr = (const float4*)(w2T + (size_t)f * AH + q * 128);
    float4 a0 = {0.f, 0.f, 0.f, 0.f}, a1 = {0.f, 0.f, 0.f, 0.f};
#pragma unroll
    for (int i = 0; i < 16; ++i) {
        float4 h0 = hr[2 * i], w0 = wr[2 * i];
        float4 h1 = hr[2 * i + 1], w1v = wr[2 * i + 1];
        a0.x += h0.x * w0.x; a0.y += h0.y * w0.y;
        a0.z += h0.z * w0.z; a0.w += h0.w * w0.w;
        a1.x += h1.x * w1v.x; a1.y += h1.y * w1v.y;
        a1.z += h1.z * w1v.z; a1.w += h1.w * w1v.w;
    }
    float p = (a0.x + a0.y) + (a0.z + a0.w) + (a1.x + a1.y) + (a1.z + a1.w);
    p += __shfl_xor(p, 1);
    p += __shfl_xor(p, 2);
    if (q == 0) out_fea[(size_t)g * FEA + f] = p + b2[f];
}

extern "C" void kernel_launch(void* const* d_in, const int* in_sizes, int n_in,
                              void* d_out, int out_size, void* d_ws, size_t ws_size,
                              hipStream_t stream) {
    const float* x     = (const float*)d_in[0];
    const int*   ei    = (const int*)d_in[1];
    const int*   batch = (const int*)d_in[2];
    const float* convW = (const float*)d_in[3];
    const float* convb = (const float*)d_in[4];
    const float* w1    = (const float*)d_in[5];
    const float* b1    = (const float*)d_in[6];
    const float* w2    = (const float*)d_in[7];
    const float* b2    = (const float*)d_in[8];
    const float* nw    = (const float*)d_in[9];
    const float* nb    = (const float*)d_in[10];
    float* out = (float*)d_out;

    // workspace layout (4-byte word offsets)
    char* wsb = (char*)d_ws;
    int*    deg    = (int*)wsb;                        // 50000
    float*  dinv   = (float*)(wsb + 50048ll * 4);      // 50000
    int*    rowptr = (int*)(wsb + 100096ll * 4);       // 50001
    int*    bsum   = (int*)(wsb + 150144ll * 4);       // 196
    int*    boff   = (int*)(wsb + 150344ll * 4);       // 196
    int*    gstart = (int*)(wsb + 150544ll * 4);       // 65
    int*    rankw  = (int*)(wsb + 150656ll * 4);       // 400000 words region (reused)
    ushort* rank   = (ushort*)rankw;                   // 800000 ushort
    // rank area reuse after k_fill:
    float*  w1T    = (float*)rankw;                    // 65536 w
    float*  w2T    = (float*)(rankw + 65536);          // 65536 w
    float*  h1ws   = (float*)(rankw + 131072);         // 32768 w
    ushort* WhiT   = (ushort*)(rankw + 163840);        // 24576 w
    ushort* WloT   = (ushort*)(rankw + 188416);        // 24576 w
    ushort* eidx   = (ushort*)(wsb + 950656ll * 4);    // <=1.3M ushort
    ushort* H      = (ushort*)(wsb + 1600672ll * 4);   // (50001)*128 bf16
    ushort* Xhi    = (ushort*)(wsb + 4800736ll * 4);   // 6.4M bf16
    ushort* Xlo    = (ushort*)(wsb + 8000736ll * 4);   // 6.4M bf16
    float*  psum_part = (float*)(wsb + 11200736ll * 4);// 1024*128 floats

    const int* srcp = ei;
    const int* dstp = ei + N_EDGES;

    // ---- CSR build + prep (once per call) ----
    hipMemsetAsync(deg, 0, N_NODES * sizeof(int), stream);
    k_deg<<<(N_EDGES + 255) / 256, 256, 0, stream>>>(dstp, deg, rank);
    k_scan1<<<NBLK, 256, 0, stream>>>(deg, rowptr, bsum, dinv);
    k_scan2<<<1, 256, 0, stream>>>(bsum, boff, rowptr);
    k_scan3<<<NBLK, 256, 0, stream>>>(rowptr, boff);
    k_fill<<<(N_EDGES + 255) / 256, 256, 0, stream>>>(srcp, dstp, rowptr, rank, eidx);
    k_prep<<<PF, 256, 0, stream>>>(x, batch, deg, rowptr, convW, w1, w2,
                                   eidx, gstart, Xhi, Xlo, WhiT, WloT, w1T, w2T, H);

    // ---- GCN layers ----
    for (int l = 0; l < NL; ++l) {
        k_gemm<<<1024, 256, 0, stream>>>(Xhi, Xlo, WhiT + (size_t)l * 16384,
                                         WloT + (size_t)l * 16384, dinv, H);
        k_gather<<<(N_NODES * 16 + 255) / 256, 256, 0, stream>>>(
            rowptr, eidx, dinv, H, convb + (size_t)l * FEA, Xhi, Xlo,
            nw, nb, out, l == NL - 1 ? 1 : 0);
    }

    // ---- heads ----
    k_pool<<<NG * 16, 256, 0, stream>>>(Xhi, Xlo, gstart, psum_part);
    k_mlp1<<<128, 256, 0, stream>>>(psum_part, gstart, w1T, b1, h1ws);
    k_mlp2<<<128, 256, 0, stream>>>(h1ws, w2T, b2, out + N_NODES);
}

// Round 11
// 256.992 us; speedup vs baseline: 1.1144x; 1.0212x over previous
//
#include <hip/hip_runtime.h>

#define N_NODES 50000
#define N_EDGES 800000
#define FEA 128
#define NL 3
#define AH 512
#define NG 64
#define NBLK 196   // ceil(50000/256)

typedef short bf16x8 __attribute__((ext_vector_type(8)));
typedef float f32x4 __attribute__((ext_vector_type(4)));
typedef uint  u32x4 __attribute__((ext_vector_type(4)));

__device__ __forceinline__ ushort f2bf(float f) {   // RTN-even
    uint u = __float_as_uint(f);
    uint r = u + 0x7FFFu + ((u >> 16) & 1u);
    return (ushort)(r >> 16);
}
__device__ __forceinline__ float bf2f(ushort u) {
    return __uint_as_float((uint)u << 16);
}

// ---------------- fused: degree+rank | x->hi/lo | convW split-T | H pad row ----------------
#define DA 3125            // deg blocks (3125*256 = 800000)
#define DB (DA + 6250)     // x conversion (6250*1024 elems)
#define DC (DB + 192)      // conv W split-transpose (3*16384)
#define DD (DC + 1)        // pad row zero
__global__ __launch_bounds__(256) void k_deg_prep(const int* __restrict__ dst,
                                                  int* __restrict__ deg,
                                                  ushort* __restrict__ rank,
                                                  const float* __restrict__ x,
                                                  ushort* __restrict__ Xhi,
                                                  ushort* __restrict__ Xlo,
                                                  const float* __restrict__ convW,
                                                  ushort* __restrict__ WhiT,
                                                  ushort* __restrict__ WloT,
                                                  ushort* __restrict__ H) {
    int blk = blockIdx.x;
    if (blk < DA) {                        // degree histogram + rank
        int i = blk * 256 + threadIdx.x;
        rank[i] = (ushort)atomicAdd(&deg[dst[i]], 1);
    } else if (blk < DB) {                 // x -> Xhi/Xlo
        int i4 = (blk - DA) * 1024 + threadIdx.x * 4;
        float4 v = *(const float4*)(x + i4);
        ushort h0 = f2bf(v.x), h1 = f2bf(v.y), h2 = f2bf(v.z), h3 = f2bf(v.w);
        uint2 hv, lv;
        hv.x = (uint)h0 | ((uint)h1 << 16);
        hv.y = (uint)h2 | ((uint)h3 << 16);
        lv.x = (uint)f2bf(v.x - bf2f(h0)) | ((uint)f2bf(v.y - bf2f(h1)) << 16);
        lv.y = (uint)f2bf(v.z - bf2f(h2)) | ((uint)f2bf(v.w - bf2f(h3)) << 16);
        *(uint2*)(Xhi + i4) = hv;
        *(uint2*)(Xlo + i4) = lv;
    } else if (blk < DC) {                 // conv W split-transpose
        int t = (blk - DB) * 256 + threadIdx.x;     // 0..49151
        int l = t >> 14, r = t & 16383;
        int k = r >> 7, c = r & 127;
        float w = convW[t];
        ushort h = f2bf(w);
        WhiT[(size_t)l * 16384 + c * FEA + k] = h;
        WloT[(size_t)l * 16384 + c * FEA + k] = f2bf(w - bf2f(h));
    } else {                               // zero H pad row
        if (threadIdx.x < 64) ((uint*)(H + (size_t)N_NODES * FEA))[threadIdx.x] = 0;
    }
}

// ---------------- 3-kernel exclusive scan over PADDED degrees ----------------
__device__ __forceinline__ int block_scan_incl(int v, int* wsum) {
    int lane = threadIdx.x & 63, w = threadIdx.x >> 6;
    int s = v;
#pragma unroll
    for (int off = 1; off < 64; off <<= 1) {
        int t = __shfl_up(s, off);
        if (lane >= off) s += t;
    }
    if (lane == 63) wsum[w] = s;
    __syncthreads();
    int woff = 0;
    for (int k = 0; k < w; ++k) woff += wsum[k];
    return woff + s;  // block-wide inclusive
}

__global__ __launch_bounds__(256) void k_scan1(const int* __restrict__ deg,
                                               int* __restrict__ rowptr,
                                               int* __restrict__ bsum,
                                               float* __restrict__ dinv) {
    __shared__ int wsum[4];
    int i = blockIdx.x * 256 + threadIdx.x;
    int v = (i < N_NODES) ? deg[i] : 0;
    int pv = (v + 7) & ~7;                       // pad to multiple of 8
    int incl = block_scan_incl(pv, wsum);
    if (i < N_NODES) {
        rowptr[i] = incl - pv;                   // local exclusive
        dinv[i] = rsqrtf((float)v + 1.0f);
    }
    if (threadIdx.x == 255) bsum[blockIdx.x] = incl;
}

__global__ __launch_bounds__(256) void k_scan2(int* __restrict__ bsum,
                                               int* __restrict__ boff,
                                               int* __restrict__ rowptr) {
    __shared__ int wsum[4];
    int v = (threadIdx.x < NBLK) ? bsum[threadIdx.x] : 0;
    int incl = block_scan_incl(v, wsum);
    if (threadIdx.x < NBLK) boff[threadIdx.x] = incl - v;
    if (threadIdx.x == NBLK - 1) rowptr[N_NODES] = incl;  // total padded edges
}

__global__ __launch_bounds__(256) void k_scan3(int* __restrict__ rowptr,
                                               const int* __restrict__ boff) {
    int i = blockIdx.x * 256 + threadIdx.x;
    if (i < N_NODES) rowptr[i] += boff[blockIdx.x];
}

// ---------------- fused: CSR fill | pad slots | graph bounds ----------------
#define FA 3125
#define FB (FA + NBLK)
#define FC (FB + NBLK)
__global__ __launch_bounds__(256) void k_fill2(const int* __restrict__ src,
                                               const int* __restrict__ dst,
                                               const int* __restrict__ rowptr,
                                               const ushort* __restrict__ rank,
                                               const int* __restrict__ deg,
                                               const int* __restrict__ batch,
                                               ushort* __restrict__ eidx,
                                               int* __restrict__ gstart) {
    int blk = blockIdx.x;
    if (blk < FA) {                        // CSR fill (no atomics)
        int e = blk * 256 + threadIdx.x;
        eidx[rowptr[dst[e]] + (int)rank[e]] = (ushort)src[e];
    } else if (blk < FB) {                 // pad slots -> zero row
        int i = (blk - FA) * 256 + threadIdx.x;
        if (i < N_NODES) {
            int d = deg[i], r = rowptr[i];
            int pd = (d + 7) & ~7;
            for (int k = d; k < pd; ++k) eidx[r + k] = (ushort)N_NODES;
        }
    } else {                               // graph bounds from sorted batch
        int i = (blk - FB) * 256 + threadIdx.x;
        if (i < N_NODES) {
            int b = batch[i];
            int bp = (i == 0) ? -1 : batch[i - 1];
            for (int g = bp + 1; g <= b; ++g) gstart[g] = i;
            if (i == N_NODES - 1)
                for (int g = b + 1; g <= NG; ++g) gstart[g] = N_NODES;
        }
    }
}

// ---------------- MFMA GEMM: H'(bf16) = dinv * (X @ W) ----------------
__global__ __launch_bounds__(256) void k_gemm(const ushort* __restrict__ Xhi,
                                              const ushort* __restrict__ Xlo,
                                              const ushort* __restrict__ WhiT,
                                              const ushort* __restrict__ WloT,
                                              const float* __restrict__ dinv,
                                              ushort* __restrict__ H) {
    const int wv = threadIdx.x >> 6;
    const int lane = threadIdx.x & 63;
    const int lr = lane & 15;
    const int lk = lane >> 4;

    bf16x8 bhi[2][4], blo[2][4];
#pragma unroll
    for (int ct = 0; ct < 2; ++ct) {
        int col = wv * 32 + ct * 16 + lr;
#pragma unroll
        for (int kf = 0; kf < 4; ++kf) {
            bhi[ct][kf] = *(const bf16x8*)(WhiT + (size_t)col * FEA + kf * 32 + lk * 8);
            blo[ct][kf] = *(const bf16x8*)(WloT + (size_t)col * FEA + kf * 32 + lk * 8);
        }
    }

    for (int rt = blockIdx.x; rt < N_NODES / 16; rt += gridDim.x) {
        int r0 = rt * 16;
        const ushort* xh = Xhi + (size_t)(r0 + lr) * FEA;
        const ushort* xl = Xlo + (size_t)(r0 + lr) * FEA;
        bf16x8 ahi[4], alo[4];
#pragma unroll
        for (int kf = 0; kf < 4; ++kf) {
            ahi[kf] = *(const bf16x8*)(xh + kf * 32 + lk * 8);
            alo[kf] = *(const bf16x8*)(xl + kf * 32 + lk * 8);
        }
        f32x4 acc0 = {0.f, 0.f, 0.f, 0.f};
        f32x4 acc1 = {0.f, 0.f, 0.f, 0.f};
#pragma unroll
        for (int kf = 0; kf < 4; ++kf) {
            acc0 = __builtin_amdgcn_mfma_f32_16x16x32_bf16(ahi[kf], bhi[0][kf], acc0, 0, 0, 0);
            acc0 = __builtin_amdgcn_mfma_f32_16x16x32_bf16(ahi[kf], blo[0][kf], acc0, 0, 0, 0);
            acc0 = __builtin_amdgcn_mfma_f32_16x16x32_bf16(alo[kf], bhi[0][kf], acc0, 0, 0, 0);
            acc1 = __builtin_amdgcn_mfma_f32_16x16x32_bf16(ahi[kf], bhi[1][kf], acc1, 0, 0, 0);
            acc1 = __builtin_amdgcn_mfma_f32_16x16x32_bf16(ahi[kf], blo[1][kf], acc1, 0, 0, 0);
            acc1 = __builtin_amdgcn_mfma_f32_16x16x32_bf16(alo[kf], bhi[1][kf], acc1, 0, 0, 0);
        }
#pragma unroll
        for (int reg = 0; reg < 4; ++reg) {
            int orow = r0 + lk * 4 + reg;
            float s = dinv[orow];
            H[(size_t)orow * FEA + wv * 32 + lr]      = f2bf(acc0[reg] * s);
            H[(size_t)orow * FEA + wv * 32 + 16 + lr] = f2bf(acc1[reg] * s);
        }
    }
}

// ---------------- gather (+fused node head on last layer) ----------------
// 16 thr/node; eidx loaded as one uint4 (8 indices) per 8-edge batch.
__global__ __launch_bounds__(256) void k_gather(const int* __restrict__ rowptr,
                                                const ushort* __restrict__ eidx,
                                                const float* __restrict__ dinv,
                                                const ushort* __restrict__ H,
                                                const float* __restrict__ b,
                                                ushort* __restrict__ Xhi,
                                                ushort* __restrict__ Xlo,
                                                const float* __restrict__ nw,
                                                const float* __restrict__ nbp,
                                                float* __restrict__ out_node,
                                                int last) {
    int t = blockIdx.x * 256 + threadIdx.x;
    int node = t >> 4;
    int c8 = t & 15;
    if (node >= N_NODES) return;
    const uint4* H4 = (const uint4*)H;  // 16 x uint4 per row
    int r0 = rowptr[node], r1 = rowptr[node + 1];

    float a[8] = {0.f, 0.f, 0.f, 0.f, 0.f, 0.f, 0.f, 0.f};
#define ACC8(u)                                                              \
    do {                                                                     \
        a[0] += __uint_as_float((u).x << 16);                                \
        a[1] += __uint_as_float((u).x & 0xffff0000u);                        \
        a[2] += __uint_as_float((u).y << 16);                                \
        a[3] += __uint_as_float((u).y & 0xffff0000u);                        \
        a[4] += __uint_as_float((u).z << 16);                                \
        a[5] += __uint_as_float((u).z & 0xffff0000u);                        \
        a[6] += __uint_as_float((u).w << 16);                                \
        a[7] += __uint_as_float((u).w & 0xffff0000u);                        \
    } while (0)

    uint4 sv = H4[(size_t)node * 16 + c8];  // self term
    ACC8(sv);

    for (int j = r0; j < r1; j += 8) {      // j is 8-aligned -> 16B-aligned
        uint4 ev = *(const uint4*)(eidx + j);
        int s0 = ev.x & 0xffff, s1 = ev.x >> 16;
        int s2 = ev.y & 0xffff, s3 = ev.y >> 16;
        int s4 = ev.z & 0xffff, s5 = ev.z >> 16;
        int s6 = ev.w & 0xffff, s7 = ev.w >> 16;
        uint4 h0 = H4[(size_t)s0 * 16 + c8];
        uint4 h1 = H4[(size_t)s1 * 16 + c8];
        uint4 h2 = H4[(size_t)s2 * 16 + c8];
        uint4 h3 = H4[(size_t)s3 * 16 + c8];
        uint4 h4 = H4[(size_t)s4 * 16 + c8];
        uint4 h5 = H4[(size_t)s5 * 16 + c8];
        uint4 h6 = H4[(size_t)s6 * 16 + c8];
        uint4 h7 = H4[(size_t)s7 * 16 + c8];
        ACC8(h0); ACC8(h1); ACC8(h2); ACC8(h3);
        ACC8(h4); ACC8(h5); ACC8(h6); ACC8(h7);
    }
#undef ACC8

    float di = dinv[node];
    const float4* b4 = (const float4*)b;
    float4 bb0 = b4[c8 * 2], bb1 = b4[c8 * 2 + 1];
    float o[8];
    o[0] = fmaxf(a[0] * di + bb0.x, 0.f);
    o[1] = fmaxf(a[1] * di + bb0.y, 0.f);
    o[2] = fmaxf(a[2] * di + bb0.z, 0.f);
    o[3] = fmaxf(a[3] * di + bb0.w, 0.f);
    o[4] = fmaxf(a[4] * di + bb1.x, 0.f);
    o[5] = fmaxf(a[5] * di + bb1.y, 0.f);
    o[6] = fmaxf(a[6] * di + bb1.z, 0.f);
    o[7] = fmaxf(a[7] * di + bb1.w, 0.f);

    if (last) {  // fused node head
        const float4* nw4 = (const float4*)nw;
        float4 n0 = nw4[c8 * 2], n1 = nw4[c8 * 2 + 1];
        float dot = o[0] * n0.x + o[1] * n0.y + o[2] * n0.z + o[3] * n0.w
                  + o[4] * n1.x + o[5] * n1.y + o[6] * n1.z + o[7] * n1.w;
        dot += __shfl_xor(dot, 1);
        dot += __shfl_xor(dot, 2);
        dot += __shfl_xor(dot, 4);
        dot += __shfl_xor(dot, 8);
        if (c8 == 0) out_node[node] = dot + nbp[0];
    }

    ushort hs[8];
    uint ls[8];
#pragma unroll
    for (int i = 0; i < 8; ++i) {
        hs[i] = f2bf(o[i]);
        ls[i] = f2bf(o[i] - bf2f(hs[i]));
    }
    u32x4 hv, lv;
    hv.x = (uint)hs[0] | ((uint)hs[1] << 16);
    hv.y = (uint)hs[2] | ((uint)hs[3] << 16);
    hv.z = (uint)hs[4] | ((uint)hs[5] << 16);
    hv.w = (uint)hs[6] | ((uint)hs[7] << 16);
    lv.x = ls[0] | (ls[1] << 16);
    lv.y = ls[2] | (ls[3] << 16);
    lv.z = ls[4] | (ls[5] << 16);
    lv.w = ls[6] | (ls[7] << 16);
    __builtin_nontemporal_store(hv, (u32x4*)(Xhi + (size_t)node * FEA + c8 * 8));
    __builtin_nontemporal_store(lv, (u32x4*)(Xlo + (size_t)node * FEA + c8 * 8));
}

// ---------------- pool-only partial sums: 16 partials per graph ----------------
__global__ __launch_bounds__(256) void k_pool(const ushort* __restrict__ Xhi,
                                              const ushort* __restrict__ Xlo,
                                              const int* __restrict__ gstart,
                                              float* __restrict__ psum_part) {
    int g = blockIdx.x >> 4, p = blockIdx.x & 15;
    int s = gstart[g], e = gstart[g + 1];
    int len = e - s;
    int lp = (len + 15) >> 4;
    int ps = s + p * lp, pe = min(ps + lp, e);
    int q = threadIdx.x >> 6, lane = threadIdx.x & 63;
    float2 acc = {0.f, 0.f};
    for (int node = ps + q; node < pe; node += 4) {
        uint hv = *(const uint*)(Xhi + (size_t)node * FEA + lane * 2);
        uint lv = *(const uint*)(Xlo + (size_t)node * FEA + lane * 2);
        acc.x += bf2f((ushort)hv) + bf2f((ushort)lv);
        acc.y += bf2f((ushort)(hv >> 16)) + bf2f((ushort)(lv >> 16));
    }
    __shared__ float lds[4 * FEA];
    lds[q * FEA + lane * 2 + 0] = acc.x;
    lds[q * FEA + lane * 2 + 1] = acc.y;
    __syncthreads();
    if (threadIdx.x < FEA) {
        psum_part[(size_t)blockIdx.x * FEA + threadIdx.x] =
            lds[threadIdx.x] + lds[FEA + threadIdx.x] +
            lds[2 * FEA + threadIdx.x] + lds[3 * FEA + threadIdx.x];
    }
}

// ---------------- MLP layer 1 (direct strided w1 reads, 4 cols/block L1-hot) ----------------
__global__ __launch_bounds__(256) void k_mlp1(const float* __restrict__ psum_part,
                                              const int* __restrict__ gstart,
                                              const float* __restrict__ w1,
                                              const float* __restrict__ b1,
                                              float* __restrict__ h1ws) {
    __shared__ float feas[NG * 132];   // pad 132 to spread banks
    for (int idx = threadIdx.x; idx < NG * FEA; idx += 256) {
        int g = idx >> 7, f = idx & 127;
        const float* pp = psum_part + (size_t)g * 16 * FEA + f;
        float sum = 0.f;
#pragma unroll
        for (int p = 0; p < 16; ++p) sum += pp[p * FEA];
        float cnt = fmaxf((float)(gstart[g + 1] - gstart[g]), 1.0f);
        feas[g * 132 + f] = sum / cnt;
    }
    __syncthreads();
    int g = threadIdx.x >> 2, jj = threadIdx.x & 3;
    int j = blockIdx.x * 4 + jj;
    const float* fr = feas + g * 132;
    float a0 = 0.f, a1 = 0.f, a2 = 0.f, a3 = 0.f;
#pragma unroll 8
    for (int k = 0; k < FEA; k += 4) {
        a0 += fr[k + 0] * w1[(k + 0) * AH + j];
        a1 += fr[k + 1] * w1[(k + 1) * AH + j];
        a2 += fr[k + 2] * w1[(k + 2) * AH + j];
        a3 += fr[k + 3] * w1[(k + 3) * AH + j];
    }
    h1ws[(size_t)g * AH + j] = fmaxf((a0 + a1) + (a2 + a3) + b1[j], 0.f);
}

// ---------------- MLP layer 2 (direct strided w2 reads, 1 col/block L1-hot) ----------------
__global__ __launch_bounds__(256) void k_mlp2(const float* __restrict__ h1ws,
                                              const float* __restrict__ w2,
                                              const float* __restrict__ b2,
                                              float* __restrict__ out_fea) {
    int f = blockIdx.x;
    int g = threadIdx.x >> 2, q = threadIdx.x & 3;
    const float* hr = h1ws + (size_t)g * AH + q * 128;
    const float* wr = w2 + (size_t)q * 128 * FEA + f;
    float a0 = 0.f, a1 = 0.f, a2 = 0.f, a3 = 0.f;
#pragma unroll 8
    for (int k = 0; k < 128; k += 4) {
        a0 += hr[k + 0] * wr[(k + 0) * FEA];
        a1 += hr[k + 1] * wr[(k + 1) * FEA];
        a2 += hr[k + 2] * wr[(k + 2) * FEA];
        a3 += hr[k + 3] * wr[(k + 3) * FEA];
    }
    float p = (a0 + a1) + (a2 + a3);
    p += __shfl_xor(p, 1);
    p += __shfl_xor(p, 2);
    if (q == 0) out_fea[(size_t)g * FEA + f] = p + b2[f];
}

extern "C" void kernel_launch(void* const* d_in, const int* in_sizes, int n_in,
                              void* d_out, int out_size, void* d_ws, size_t ws_size,
                              hipStream_t stream) {
    const float* x     = (const float*)d_in[0];
    const int*   ei    = (const int*)d_in[1];
    const int*   batch = (const int*)d_in[2];
    const float* convW = (const float*)d_in[3];
    const float* convb = (const float*)d_in[4];
    const float* w1    = (const float*)d_in[5];
    const float* b1    = (const float*)d_in[6];
    const float* w2    = (const float*)d_in[7];
    const float* b2    = (const float*)d_in[8];
    const float* nw    = (const float*)d_in[9];
    const float* nb    = (const float*)d_in[10];
    float* out = (float*)d_out;

    // workspace layout (4-byte word offsets)
    char* wsb = (char*)d_ws;
    int*    deg    = (int*)wsb;                        // 50000
    float*  dinv   = (float*)(wsb + 50048ll * 4);      // 50000
    int*    rowptr = (int*)(wsb + 100096ll * 4);       // 50001
    int*    bsum   = (int*)(wsb + 150144ll * 4);       // 196
    int*    boff   = (int*)(wsb + 150344ll * 4);       // 196
    int*    gstart = (int*)(wsb + 150544ll * 4);       // 65
    int*    rankw  = (int*)(wsb + 150656ll * 4);       // 400000 words
    ushort* rank   = (ushort*)rankw;                   // 800000 ushort
    float*  h1ws   = (float*)rankw;                    // 32768 w (after fill)
    ushort* eidx   = (ushort*)(wsb + 950656ll * 4);    // <=1.3M ushort
    ushort* H      = (ushort*)(wsb + 1600672ll * 4);   // (50001)*128 bf16
    ushort* Xhi    = (ushort*)(wsb + 4800736ll * 4);   // 6.4M bf16
    ushort* Xlo    = (ushort*)(wsb + 8000736ll * 4);   // 6.4M bf16
    float*  psum_part = (float*)(wsb + 11200736ll * 4);// 1024*128 floats
    // WhiT/WloT alias psum_part: dead after last gemm, psum written by k_pool later
    ushort* WhiT   = (ushort*)psum_part;               // 49152 shorts
    ushort* WloT   = WhiT + 49152;                     // 49152 shorts

    const int* srcp = ei;
    const int* dstp = ei + N_EDGES;

    // ---- CSR build + prep ----
    hipMemsetAsync(deg, 0, N_NODES * sizeof(int), stream);
    k_deg_prep<<<DD, 256, 0, stream>>>(dstp, deg, rank, x, Xhi, Xlo, convW, WhiT, WloT, H);
    k_scan1<<<NBLK, 256, 0, stream>>>(deg, rowptr, bsum, dinv);
    k_scan2<<<1, 256, 0, stream>>>(bsum, boff, rowptr);
    k_scan3<<<NBLK, 256, 0, stream>>>(rowptr, boff);
    k_fill2<<<FC, 256, 0, stream>>>(srcp, dstp, rowptr, rank, deg, batch, eidx, gstart);

    // ---- GCN layers ----
    for (int l = 0; l < NL; ++l) {
        k_gemm<<<1024, 256, 0, stream>>>(Xhi, Xlo, WhiT + (size_t)l * 16384,
                                         WloT + (size_t)l * 16384, dinv, H);
        k_gather<<<(N_NODES * 16 + 255) / 256, 256, 0, stream>>>(
            rowptr, eidx, dinv, H, convb + (size_t)l * FEA, Xhi, Xlo,
            nw, nb, out, l == NL - 1 ? 1 : 0);
    }

    // ---- heads ----
    k_pool<<<NG * 16, 256, 0, stream>>>(Xhi, Xlo, gstart, psum_part);
    k_mlp1<<<128, 256, 0, stream>>>(psum_part, gstart, w1, b1, h1ws);
    k_mlp2<<<128, 256, 0, stream>>>(h1ws, w2, b2, out + N_NODES);
}